// Round 1
// baseline (79.385 us; speedup 1.0000x reference)
//
#include <hip/hip_runtime.h>
#include <math.h>

#define VOX 64
#define NPOLY 32
#define NEDGE 32
#define NET (NPOLY * NEDGE)   // 1024 edges

// DPP-based partial min: combine x with a row-shifted copy of x.
// old = +INF so lanes whose DPP source is invalid contribute identity.
template<int CTRL>
__device__ __forceinline__ float dppmin(float x) {
    int s = __builtin_amdgcn_update_dpp(0x7f800000, __float_as_int(x),
                                        CTRL, 0xF, 0xF, false);
    return fminf(x, __int_as_float(s));
}

// block = 512 threads = 8 waves; grid = B*64 rows = 512 blocks (2 blocks/CU)
// Lane layout in the SDF loop: lane = (half h = l>>5, edge k = l&31).
// Each wave sweeps all 64 pixels of its row for its polygons (j = g, g+8, ...),
// evaluating pixels 2p+0 (half 0) and 2p+1 (half 1) per step.
__global__ __launch_bounds__(512, 2) void extrusion_kernel(
    const float* __restrict__ polygons,    // (B,32,32,2)
    const float* __restrict__ attributes,  // (B,4)
    const float* __restrict__ validity,    // (B,32)
    float* __restrict__ out)               // (B,64,64,64)
{
    __shared__ float4 ecA[NET];        // x0, ex, ey, inv_norm2
    __shared__ float4 ecB[NET];        // c1 = vy*ey, vy, ix (-1e30 if no y-cross), pad
    __shared__ float  partial[8][VOX];
    __shared__ float  comb[VOX];
    __shared__ int    vIdx[NPOLY];
    __shared__ int    nValidS;

    const int t   = threadIdx.x;
    const int b   = blockIdx.x >> 6;   // batch
    const int row = blockIdx.x & 63;   // y index
    const float py = (float)row * (1.0f / 63.0f);

    // ---- validity compaction: ballot + prefix popcount (first wave) ----
    if (t < 64) {
        bool f = (t < NPOLY) && (validity[b * NPOLY + t] >= 0.5f);
        unsigned long long m = __ballot(f);
        if (f) vIdx[__popcll(m & ((1ull << t) - 1ull))] = t;
        if (t == 0) nValidS = (int)__popcll(m);
    }

    // ---- per-row edge constants: 2 edges per thread (unchanged) ----
    const float2* pb = (const float2*)(polygons + (size_t)b * NET * 2);
    for (int e = t; e < NET; e += 512) {
        int n  = e >> 5;
        int k  = e & 31;
        int k1 = (k + 1) & 31;
        float2 v0 = pb[n * NEDGE + k];
        float2 v1 = pb[n * NEDGE + k1];
        float ex = v1.x - v0.x;
        float ey = v1.y - v0.y;
        float inv = 1.0f / (ex * ex + ey * ey + 1e-8f);
        float vy  = py - v0.y;
        float c1  = vy * ey;
        bool ycross = ((v0.y <= py) && (v1.y > py)) || ((v1.y <= py) && (v0.y > py));
        float ix = ycross ? (v0.x + ex * (vy / (ey + 1e-8f))) : -1e30f;
        ecA[e] = make_float4(v0.x, ex, ey, inv);
        ecB[e] = make_float4(c1, vy, ix, 0.0f);
    }
    __syncthreads();

    // ---- SDF: lane = edge, loop over pixels; constants live in registers ----
    const int g  = t >> 6;             // wave id 0..7 (wave-uniform)
    const int l  = t & 63;             // hardware lane
    const int ke = l & 31;             // edge index within poly
    const float hx = (float)(l >> 5) * (1.0f / 63.0f);  // pixel-parity offset
    const int halfp = l >> 1;          // owner pair index (lane q owns pixel q)
    const int lodd  = l & 1;
    const int nV = nValidS;

    // acc holds a sign-carrying d^2 key: key = inside ? -d2 : d2.
    // min over keys == min over signed distances (sqrt is monotone), so the
    // final result is bit-identical to per-poly sqrt-then-min.
    float acc = 1e36f;
    for (int j = g; j < nV; j += 8) {
        const int e0 = vIdx[j] * NEDGE + ke;     // lane-distinct, conflict-free
        const float4 A  = ecA[e0];               // 2 x ds_read_b128 per wave-poly
        const float4 Bc = ecB[e0];
        #pragma unroll 8
        for (int p = 0; p < 32; ++p) {
            // half 0 evaluates pixel 2p, half 1 evaluates pixel 2p+1
            float px  = fmaf((float)p, 2.0f / 63.0f, hx);
            float vx  = px - A.x;
            float w   = fmaf(vx, A.y, Bc.x);              // v.e
            float tt  = fminf(fmaxf(w * A.w, 0.0f), 1.0f);
            float dx  = fmaf(-tt, A.y, vx);
            float dy  = fmaf(-tt, A.z, Bc.y);
            float d2  = fmaf(dy, dy, dx * dx);
            // min over the 32 edges of each half via DPP (VALU pipe, no LDS)
            float m = d2;
            m = dppmin<0x111>(m);   // row_shr:1
            m = dppmin<0x112>(m);   // row_shr:2
            m = dppmin<0x114>(m);   // row_shr:4
            m = dppmin<0x118>(m);   // row_shr:8  -> lane15/31/47/63 hold row mins
            m = dppmin<0x142>(m);   // row_bcast15 -> lane31 = min(0..31), lane63 = min(32..63)
            float m0 = __int_as_float(__builtin_amdgcn_readlane(__float_as_int(m), 31));
            float m1 = __int_as_float(__builtin_amdgcn_readlane(__float_as_int(m), 63));
            // crossing parity per half (scalar pipe)
            unsigned long long cm = __ballot(Bc.z > px);
            int par0 = ((int)__popcll(cm & 0xffffffffull)) & 1;
            int par1 = ((int)__popcll(cm >> 32)) & 1;
            float k0 = par0 ? -m0 : m0;          // key for pixel 2p
            float k1 = par1 ? -m1 : m1;          // key for pixel 2p+1
            float kk = lodd ? k1 : k0;
            acc = (halfp == p) ? fminf(acc, kk) : acc;  // lanes 2p,2p+1 own these pixels
        }
    }
    {
        float ad = sqrtf(fabsf(acc));            // one sqrt per pixel, at the end
        partial[g][l] = (acc < 0.0f) ? -ad : ad; // signed distance
    }
    __syncthreads();

    // ---- reduce 8 groups -> one sigmoid per pixel (sigmoid monotone) ----
    if (t < VOX) {
        float m = partial[0][t];
        #pragma unroll
        for (int gg = 1; gg < 8; ++gg) m = fminf(m, partial[gg][t]);
        // nV==0 -> m=1e18 -> expf(inf) -> comb=0 (matches reference)
        comb[t] = 1.0f / (1.0f + __expf(100.0f * m));
    }
    __syncthreads();

    // ---- extrusion epilogue: h = clip(floor(att0*64), 1, 64) ----
    float att = attributes[b * 4 + 0];
    int h = max(1, min(64, (int)floorf(att * 64.0f)));

    float4* out4 = (float4*)out;
    const int q  = t & 15;             // float4 column
    const int z0 = t >> 4;             // 0..31
    float4 cv = make_float4(comb[q * 4 + 0], comb[q * 4 + 1],
                            comb[q * 4 + 2], comb[q * 4 + 3]);
    float4 zero = make_float4(0.f, 0.f, 0.f, 0.f);
    size_t base4 = (size_t)b * 65536 + (size_t)row * 16 + q;  // /4 indexing
    out4[base4 + (size_t)z0 * 1024]        = (z0 < h)        ? cv : zero;
    out4[base4 + (size_t)(z0 + 32) * 1024] = ((z0 + 32) < h) ? cv : zero;
}

extern "C" void kernel_launch(void* const* d_in, const int* in_sizes, int n_in,
                              void* d_out, int out_size, void* d_ws, size_t ws_size,
                              hipStream_t stream) {
    const float* polygons   = (const float*)d_in[0];
    const float* attributes = (const float*)d_in[1];
    const float* validity   = (const float*)d_in[2];
    float* out = (float*)d_out;
    const int B = in_sizes[2] / NPOLY;   // 8
    dim3 grid(B * VOX);                  // 512 blocks
    dim3 block(512);
    extrusion_kernel<<<grid, block, 0, stream>>>(polygons, attributes, validity, out);
}

// Round 2
// 69.831 us; speedup vs baseline: 1.1368x; 1.1368x over previous
//
#include <hip/hip_runtime.h>
#include <math.h>

#define VOX 64
#define NPOLY 32
#define NEDGE 32
#define NET (NPOLY * NEDGE)   // 1024 edges

// block = 1024 threads = 16 waves; grid = B*64 rows = 512 blocks -> 2 blocks/CU
// -> 32 waves/CU = 8 waves/SIMD (2x round-0 occupancy), provided VGPR <= 64
// (__launch_bounds__(1024,8): 8 waves/EU * 4 EU / 16 waves-per-block = 2 blocks/CU).
__global__ __launch_bounds__(1024, 8) void extrusion_kernel(
    const float* __restrict__ polygons,    // (B,32,32,2)
    const float* __restrict__ attributes,  // (B,4)
    const float* __restrict__ validity,    // (B,32)
    float* __restrict__ out)               // (B,64,64,64)
{
    __shared__ float4 ecA[NET];        // x0, ex, ey, inv_norm2
    __shared__ float4 ecB[NET];        // c1 = vy*ey, vy, ix (-1e30 if no y-cross), pad
    __shared__ float  partial[16][VOX];
    __shared__ float  comb[VOX];
    __shared__ int    vIdx[NPOLY];
    __shared__ int    nValidS;

    const int t   = threadIdx.x;
    const int b   = blockIdx.x >> 6;   // batch
    const int row = blockIdx.x & 63;   // y index
    const float py = (float)row * (1.0f / 63.0f);

    // ---- validity compaction: ballot + prefix popcount (first wave) ----
    if (t < 64) {
        bool f = (t < NPOLY) && (validity[b * NPOLY + t] >= 0.5f);
        unsigned long long m = __ballot(f);
        if (f) vIdx[__popcll(m & ((1ull << t) - 1ull))] = t;
        if (t == 0) nValidS = (int)__popcll(m);
    }

    // ---- per-row edge constants: exactly 1 edge per thread ----
    const float2* pb = (const float2*)(polygons + (size_t)b * NET * 2);
    {
        const int e  = t;              // 1024 threads, 1024 edges
        const int n  = e >> 5;
        const int k  = e & 31;
        const int k1 = (k + 1) & 31;
        float2 v0 = pb[n * NEDGE + k];
        float2 v1 = pb[n * NEDGE + k1];
        float ex = v1.x - v0.x;
        float ey = v1.y - v0.y;
        float inv = 1.0f / (ex * ex + ey * ey + 1e-8f);
        float vy  = py - v0.y;
        float c1  = vy * ey;
        bool ycross = ((v0.y <= py) && (v1.y > py)) || ((v1.y <= py) && (v0.y > py));
        float ix = ycross ? (v0.x + ex * (vy / (ey + 1e-8f))) : -1e30f;
        ecA[e] = make_float4(v0.x, ex, ey, inv);
        ecB[e] = make_float4(c1, vy, ix, 0.0f);
    }
    __syncthreads();

    // ---- SDF over compacted valid polygons: ~1 poly per wave ----
    const int g  = t >> 6;             // wave id 0..15 (wave-uniform)
    const int lx = t & 63;             // pixel x
    const float px = (float)lx * (1.0f / 63.0f);
    const int nV = nValidS;

    // acc holds a sign-carrying d^2 key: key = inside ? -d2 : d2.
    // min over keys == min over signed distances (sqrt monotone) -> bit-identical.
    float acc = 1e36f;
    for (int j = g; j < nV; j += 16) {
        const int base = vIdx[j] * NEDGE;    // wave-uniform
        // 4 independent min-trees + 2 crossing counters: dep chain 32 -> 8
        float mv0 = 1e30f, mv1 = 1e30f, mv2 = 1e30f, mv3 = 1e30f;
        int   c0 = 0, c1n = 0;
        #pragma unroll 4
        for (int k = 0; k < NEDGE; k += 2) {
            float4 A0  = ecA[base + k];
            float4 B0  = ecB[base + k];
            float4 A1  = ecA[base + k + 1];
            float4 B1  = ecB[base + k + 1];

            float vx0  = px - A0.x;
            float dot0 = fmaf(vx0, A0.y, B0.x);
            float tt0  = fminf(fmaxf(dot0 * A0.w, 0.0f), 1.0f);
            float dx0  = fmaf(-tt0, A0.y, vx0);
            float dy0  = fmaf(-tt0, A0.z, B0.y);
            float d20  = fmaf(dy0, dy0, dx0 * dx0);

            float vx1  = px - A1.x;
            float dot1 = fmaf(vx1, A1.y, B1.x);
            float tt1  = fminf(fmaxf(dot1 * A1.w, 0.0f), 1.0f);
            float dx1  = fmaf(-tt1, A1.y, vx1);
            float dy1  = fmaf(-tt1, A1.z, B1.y);
            float d21  = fmaf(dy1, dy1, dx1 * dx1);

            if ((k & 2) == 0) { mv0 = fminf(mv0, d20); mv1 = fminf(mv1, d21); }
            else              { mv2 = fminf(mv2, d20); mv3 = fminf(mv3, d21); }
            c0  += (B0.z > px) ? 1 : 0;
            c1n += (B1.z > px) ? 1 : 0;
        }
        float mind2 = fminf(fminf(mv0, mv1), fminf(mv2, mv3));
        int cnt = c0 + c1n;
        float key = (cnt & 1) ? -mind2 : mind2;
        acc = fminf(acc, key);
    }
    {
        float ad = sqrtf(fabsf(acc));            // one sqrt per pixel-slot
        partial[g][lx] = (acc < 0.0f) ? -ad : ad;
    }
    __syncthreads();

    // ---- reduce 16 groups -> one sigmoid per pixel (sigmoid monotone) ----
    if (t < VOX) {
        float m = partial[0][t];
        #pragma unroll
        for (int gg = 1; gg < 16; ++gg) m = fminf(m, partial[gg][t]);
        // nV==0 -> m=1e18 -> expf(inf) -> comb=0 (matches reference)
        comb[t] = 1.0f / (1.0f + __expf(100.0f * m));
    }
    __syncthreads();

    // ---- extrusion epilogue: h = clip(floor(att0*64), 1, 64) ----
    float att = attributes[b * 4 + 0];
    int h = max(1, min(64, (int)floorf(att * 64.0f)));

    // 1024 threads: one float4 per thread covers all 64 z-slices of this row
    float4* out4 = (float4*)out;
    const int q = t & 15;              // float4 column
    const int z = t >> 4;              // 0..63
    float4 cv = make_float4(comb[q * 4 + 0], comb[q * 4 + 1],
                            comb[q * 4 + 2], comb[q * 4 + 3]);
    float4 zero = make_float4(0.f, 0.f, 0.f, 0.f);
    size_t base4 = (size_t)b * 65536 + (size_t)row * 16 + q;  // /4 indexing
    out4[base4 + (size_t)z * 1024] = (z < h) ? cv : zero;
}

extern "C" void kernel_launch(void* const* d_in, const int* in_sizes, int n_in,
                              void* d_out, int out_size, void* d_ws, size_t ws_size,
                              hipStream_t stream) {
    const float* polygons   = (const float*)d_in[0];
    const float* attributes = (const float*)d_in[1];
    const float* validity   = (const float*)d_in[2];
    float* out = (float*)d_out;
    const int B = in_sizes[2] / NPOLY;   // 8
    dim3 grid(B * VOX);                  // 512 blocks
    dim3 block(1024);
    extrusion_kernel<<<grid, block, 0, stream>>>(polygons, attributes, validity, out);
}